// Round 6
// baseline (1818.378 us; speedup 1.0000x reference)
//
#include <hip/hip_runtime.h>
#include <stdint.h>

// GRU decoder: 65536 rows, H=256, T=12, D_OUT=64.
// 512 blocks x 512 threads (8 waves; two 64-row groups; 2 waves/SIMD).
// Weights stream through a ring-3 of 32KB LDS panels (global_load_lds,
// vmcnt(4), staged 2 phases ahead). Phase order per step:
//   W1(4) -> z(4) -> r(4) -> W2(4)+combine -> proj
// A-operands in regs (h for W1/z/r, rh for W2, h_new for proj).
// LDS layout, chunk-XOR: L(row,b) = (row>>3)*4096 + (b>>4)*128
//   + (((row&7) ^ ((b>>4)&7))<<4) + (b&15)   -- elementwise conflict-free.
// NOTE: __launch_bounds__ 2nd arg behaves as min BLOCKS/CU (CUDA semantics):
// (512,2) capped VGPRs at 128 -> massive scratch spill (R4/R5 WRITE_SIZE
// 2.25GB). (512,1) allows 256 VGPRs = the live set.

#define NROWS   65536
#define TSTEPS  12

typedef _Float16 f16x8  __attribute__((ext_vector_type(8)));
typedef _Float16 f16x4  __attribute__((ext_vector_type(4)));
typedef _Float16 f16x16v __attribute__((ext_vector_type(16)));
typedef float    f32x16 __attribute__((ext_vector_type(16)));

// ws layout (f16): Wg_folded[512][256] | W1[256][256] | W2[256][256] | Wp[64][256]
// panel q = 64 rows x 256 k = 32KB: 0-3 gate-r, 4-7 gate-z, 8-11 W1, 12-15 W2, 16 Wp
#define WG_E   (512*256)
#define W1_E   (256*256)
#define WS_F16_TOTAL (WG_E + 2*W1_E + 64*256)

__global__ void prep_weights(const float* __restrict__ gw,
                             const float* __restrict__ ow,
                             const float* __restrict__ pw,
                             _Float16* __restrict__ ws)
{
    int idx = blockIdx.x*256 + threadIdx.x;
    if (idx < WG_E) {                      // folded gates
        int j = idx >> 8, k = idx & 255;
        ws[idx] = (_Float16)(gw[j*512 + k] + gw[j*512 + 256 + k]);
    } else if (idx < WG_E + W1_E) {        // W1 = out_w[:, :256]
        int i = idx - WG_E; int r = i >> 8, c = i & 255;
        ws[idx] = (_Float16)ow[r*512 + c];
    } else if (idx < WG_E + 2*W1_E) {      // W2 = out_w[:, 256:]
        int i = idx - WG_E - W1_E; int r = i >> 8, c = i & 255;
        ws[idx] = (_Float16)ow[r*512 + 256 + c];
    } else if (idx < WS_F16_TOTAL) {       // Wp
        ws[idx] = (_Float16)pw[idx - WG_E - 2*W1_E];
    }
}

__device__ __forceinline__ float sigm(float x)  { return 1.0f/(1.0f+__expf(-x)); }
__device__ __forceinline__ float tanh_(float x) { return 1.0f - 2.0f/(1.0f+__expf(2.0f*x)); }

// stage one 32KB panel cooperatively (8 waves x 4 gll16). LDS dest linear;
// global source carries the inverse chunk-XOR permutation.
__device__ __forceinline__ void stage(const uint8_t* __restrict__ Wp,
                                      uint8_t* slot_, int w, int lane)
{
    #pragma unroll
    for (int i = 0; i < 4; ++i) {
        int d  = w*4096 + i*1024;              // wave-uniform LDS offset
        int dl = d + lane*16;
        int chunk = (dl>>7)&31;
        int sl    = (dl>>4)&7;
        int row   = ((dl>>12)<<3) | (sl ^ (chunk&7));
        int s     = row*512 + chunk*16;
        __builtin_amdgcn_global_load_lds(
            (const __attribute__((address_space(1))) uint32_t*)(Wp + s),
            (__attribute__((address_space(3))) uint32_t*)(slot_ + d),
            16, 0, 0);
    }
}

struct Bases { const uint8_t* p[4]; };

__device__ __forceinline__ Bases mkbases(const uint8_t* base, int off, int u2) {
    Bases b;
    #pragma unroll
    for (int j = 0; j < 4; ++j) b.p[j] = base + off + (u2 ^ (j<<5));
    return b;
}
__device__ __forceinline__ void ldA(f16x8* A, const Bases& aB) {
    #pragma unroll
    for (int ks = 0; ks < 16; ++ks)
        A[ks] = *(const f16x8*)(aB.p[ks&3] + ks*256);
}
__device__ __forceinline__ f32x16 gemm4(const Bases& bb, const f16x8* A, f32x16 acc) {
    #pragma unroll
    for (int ks = 0; ks < 16; ++ks) {
        f16x8 b = *(const f16x8*)(bb.p[ks&3] + ks*256);
        acc = __builtin_amdgcn_mfma_f32_32x32x16_f16(A[ks], b, acc, 0, 0, 0);
    }
    return acc;
}

// phase: wait compute-slot loads -> barrier -> stage 2-ahead -> compute
#define PH(SP, ...) do {                                                    \
    asm volatile("s_waitcnt vmcnt(4)" ::: "memory");                        \
    asm volatile("s_waitcnt lgkmcnt(0)" ::: "memory");                      \
    __builtin_amdgcn_s_barrier();                                           \
    asm volatile("" ::: "memory");                                          \
    { int sS = sC + 2; if (sS >= 3) sS -= 3;                                \
      stage(W + (size_t)(SP)*32768, Wb + sS*32768, w, lane); }              \
    { const uint8_t* pan = Wb + sC*32768;                                   \
      Bases bb = mkbases(pan, Bc, u2); (void)bb; __VA_ARGS__; }             \
    sC = (sC == 2) ? 0 : sC + 1;                                            \
} while (0)

__global__ __launch_bounds__(512, 1)
void gru_dec(const float* __restrict__ h_in, const _Float16* __restrict__ Wf,
             const float* __restrict__ gate_b, const float* __restrict__ out_b,
             const float* __restrict__ proj_b, float* __restrict__ out)
{
    __shared__ __align__(16) uint8_t lds[163840];
    uint8_t* Wb = lds + 65536;                 // 3 x 32KB panel ring
    const uint8_t* W = (const uint8_t*)Wf;

    const int tid  = threadIdx.x;
    const int lane = tid & 63;
    const int w    = tid >> 6;                 // 0..7
    const int g    = w >> 2;                   // row group 0/1
    const int wl   = w & 3;
    const int mhat = wl >> 1, nhat = wl & 1;
    const int kg   = lane >> 5, bl = lane & 31;
    uint8_t* Ht = lds + g*32768;               // [64 rows][256 f16], chunk-XOR
    const int row0 = blockIdx.x*128 + g*64;

    // ---- initial h: 512 threads cover 128 rows x 256 cols, f32 -> f16 ----
    {
        int r  = tid >> 2;                     // 0..127
        int lr = r & 63;
        uint8_t* gb2 = lds + (r>>6)*32768 + (lr>>3)*4096;
        int sl7 = lr & 7;
        const float* src = h_in + (size_t)(blockIdx.x*128 + r)*256 + (tid&3)*64;
        #pragma unroll
        for (int i = 0; i < 16; ++i) {
            float4 v = *(const float4*)(src + i*4);
            f16x4 p = {(_Float16)v.x,(_Float16)v.y,(_Float16)v.z,(_Float16)v.w};
            int c = (tid&3)*64 + i*4;
            int chunk = c>>3;
            *(f16x4*)(gb2 + chunk*128 + ((sl7 ^ (chunk&7))<<4) + (c&7)*2) = p;
        }
    }

    float rb[4], zb[4], ob2[4];
    #pragma unroll
    for (int k = 0; k < 4; ++k) {
        int c = k*64 + nhat*32 + bl;
        rb[k] = gate_b[c]; zb[k] = gate_b[256 + c]; ob2[k] = out_b[c];
    }
    const float pb = proj_b[nhat*32 + bl];

    // per-lane addressing constants
    const int u2 = ((bl&7) ^ kg) << 4;
    const int Bc = (nhat*4 + (bl>>3))*4096 + kg*128;     // B page base in panel
    const int Ac = (mhat*4 + (bl>>3))*4096 + kg*128;     // A page base in Ht
    const int q  = nhat*4 + (bl>>3);
    const int m16 = ((kg<<2) ^ q) << 4;
    const int E0 = mhat*16384 + q*128 + (bl&7)*2;
    uint8_t* X[4];
    #pragma unroll
    for (int j = 0; j < 4; ++j) X[j] = Ht + E0 + ((j*16) ^ m16);
    const Bases aB = mkbases(Ht, Ac, u2);

    __syncthreads();

    f16x8 A[16];
    ldA(A, aB);                                // A = h

    stage(W + 8*32768, Wb,         w, lane);   // prologue: panels 8,9
    stage(W + 9*32768, Wb + 32768, w, lane);
    int sC = 0;

    for (int t = 0; t < TSTEPS; ++t) {
        f32x16 oa0, oa1, oa2, oa3;
        f16x16v zz[4], hold[4];

        // ---- W1 (panels 8..11): oa_k = h @ W1_k^T ----
        PH(10, { f32x16 a_ = {}; oa0 = gemm4(bb, A, a_); });
        PH(11, { f32x16 a_ = {}; oa1 = gemm4(bb, A, a_); });
        PH(4,  { f32x16 a_ = {}; oa2 = gemm4(bb, A, a_); });
        PH(5,  { f32x16 a_ = {}; oa3 = gemm4(bb, A, a_); });

        // ---- z gates (panels 4..7): zz_k f16 in regs ----
#define ZPH(SPAN, K)                                                          \
        PH(SPAN, { f32x16 acc = {}; acc = gemm4(bb, A, acc);                  \
            _Pragma("unroll")                                                 \
            for (int e = 0; e < 16; ++e)                                      \
                zz[K][e] = (_Float16)sigm(acc[e] + zb[K]); })
        ZPH(6, 0); ZPH(7, 1); ZPH(0, 2); ZPH(1, 3);
#undef ZPH

        // ---- r gates (panels 0..3): capture h_old, write rh over Ht band k ----
#define RPH(SPAN, K)                                                          \
        PH(SPAN, { f32x16 acc = {}; acc = gemm4(bb, A, acc);                  \
            _Pragma("unroll")                                                 \
            for (int e = 0; e < 16; ++e) {                                    \
                uint8_t* p = X[e&3] + (K)*1024 + (e>>2)*4096;                 \
                float hc = (float)*(const _Float16*)p;                        \
                hold[K][e] = (_Float16)hc;                                    \
                *(_Float16*)p = (_Float16)(sigm(acc[e] + rb[K]) * hc);        \
            } })
        RPH(2, 0); RPH(3, 1); RPH(12, 2); RPH(13, 3);
#undef RPH

        // ---- W2 (panels 12..15): oa_k += rh @ W2_k^T; combine; write h_new ----
        PH(14, {
            ldA(A, aB);                                     // A = rh (all bands)
            asm volatile("s_waitcnt lgkmcnt(0)" ::: "memory");
            __builtin_amdgcn_s_barrier();                   // all waves loaded rh
            asm volatile("" ::: "memory");
            oa0 = gemm4(bb, A, oa0);
            _Pragma("unroll")
            for (int e = 0; e < 16; ++e) {
                float u = tanh_(oa0[e] + ob2[0]);
                float z = (float)zz[0][e];
                uint8_t* p = X[e&3] + 0*1024 + (e>>2)*4096;
                *(_Float16*)p = (_Float16)(z*(float)hold[0][e] + (1.0f - z)*u);
            } });
#define W2PH(SPAN, K, OA)                                                     \
        PH(SPAN, { OA = gemm4(bb, A, OA);                                     \
            _Pragma("unroll")                                                 \
            for (int e = 0; e < 16; ++e) {                                    \
                float u = tanh_(OA[e] + ob2[K]);                              \
                float z = (float)zz[K][e];                                    \
                uint8_t* p = X[e&3] + (K)*1024 + (e>>2)*4096;                 \
                *(_Float16*)p = (_Float16)(z*(float)hold[K][e] + (1.0f - z)*u); \
            } })
        W2PH(15, 1, oa1); W2PH(16, 2, oa2); W2PH(8, 3, oa3);
#undef W2PH

        // ---- proj (panel 16): A <- h_new; out_t = h_new @ Wp^T + pb ----
        PH(9, {
            ldA(A, aB);                                     // A = h_new
            f32x16 acc = {}; acc = gemm4(bb, A, acc);
            _Pragma("unroll")
            for (int e = 0; e < 16; ++e) {
                int row = mhat*32 + (e&3) + 8*(e>>2) + 4*kg;
                __builtin_nontemporal_store(acc[e] + pb,
                    &out[((size_t)(row0 + row)*TSTEPS + t)*64 + nhat*32 + bl]);
            } });
    }
}

extern "C" void kernel_launch(void* const* d_in, const int* in_sizes, int n_in,
                              void* d_out, int out_size, void* d_ws, size_t ws_size,
                              hipStream_t stream) {
    // inputs: 0:x(=12) 1:h 2:gate_w 3:gate_b 4:out_w 5:out_b 6:proj_w 7:proj_b
    const float* h  = (const float*)d_in[1];
    const float* gw = (const float*)d_in[2];
    const float* gb = (const float*)d_in[3];
    const float* ow = (const float*)d_in[4];
    const float* ob = (const float*)d_in[5];
    const float* pw = (const float*)d_in[6];
    const float* pb = (const float*)d_in[7];
    if (ws_size < (size_t)WS_F16_TOTAL * sizeof(_Float16)) return;
    _Float16* ws = (_Float16*)d_ws;

    hipLaunchKernelGGL(prep_weights, dim3((WS_F16_TOTAL + 255)/256), dim3(256), 0, stream,
                       gw, ow, pw, ws);
    hipLaunchKernelGGL(gru_dec, dim3(NROWS/128), dim3(512), 0, stream,
                       h, ws, gb, ob, pb, (float*)d_out);
}

// Round 7
// 1167.214 us; speedup vs baseline: 1.5579x; 1.5579x over previous
//
#include <hip/hip_runtime.h>
#include <stdint.h>

// GRU decoder: 65536 rows, H=256, T=12, D_OUT=64.
// 512 blocks x 512 threads (8 waves; two 64-row groups; 2 waves/SIMD).
// Weights stream through a ring-3 of 32KB LDS panels (global_load_lds,
// vmcnt(4), staged 2 phases ahead). Phase order per step:
//   W1(4) -> z(4) -> r(4) -> W2(4)+combine -> proj
// A-operands in regs (h for W1/z/r, rh for W2, h_new for proj).
// LDS layout, chunk-XOR: L(row,b) = (row>>3)*4096 + (b>>4)*128
//   + (((row&7) ^ ((b>>4)&7))<<4) + (b&15)   -- elementwise conflict-free.
// REGISTER BUDGET (R6 lesson): LDS=160KB -> 1 block/CU -> 2 waves/SIMD ->
// 256 unified VGPR+AGPR per wave. R5/R6 live set ~280 spilled ~2GB to
// scratch (WRITE_SIZE signature). Fix: W1 partials held as f16 (oaH, 32
// regs) instead of f32 (64), re-expanded as MFMA C-in at W2.

#define NROWS   65536
#define TSTEPS  12

typedef _Float16 f16x8  __attribute__((ext_vector_type(8)));
typedef _Float16 f16x4  __attribute__((ext_vector_type(4)));
typedef _Float16 f16x16v __attribute__((ext_vector_type(16)));
typedef float    f32x16 __attribute__((ext_vector_type(16)));

// ws layout (f16): Wg_folded[512][256] | W1[256][256] | W2[256][256] | Wp[64][256]
// panel q = 64 rows x 256 k = 32KB: 0-3 gate-r, 4-7 gate-z, 8-11 W1, 12-15 W2, 16 Wp
#define WG_E   (512*256)
#define W1_E   (256*256)
#define WS_F16_TOTAL (WG_E + 2*W1_E + 64*256)

__global__ void prep_weights(const float* __restrict__ gw,
                             const float* __restrict__ ow,
                             const float* __restrict__ pw,
                             _Float16* __restrict__ ws)
{
    int idx = blockIdx.x*256 + threadIdx.x;
    if (idx < WG_E) {                      // folded gates
        int j = idx >> 8, k = idx & 255;
        ws[idx] = (_Float16)(gw[j*512 + k] + gw[j*512 + 256 + k]);
    } else if (idx < WG_E + W1_E) {        // W1 = out_w[:, :256]
        int i = idx - WG_E; int r = i >> 8, c = i & 255;
        ws[idx] = (_Float16)ow[r*512 + c];
    } else if (idx < WG_E + 2*W1_E) {      // W2 = out_w[:, 256:]
        int i = idx - WG_E - W1_E; int r = i >> 8, c = i & 255;
        ws[idx] = (_Float16)ow[r*512 + 256 + c];
    } else if (idx < WS_F16_TOTAL) {       // Wp
        ws[idx] = (_Float16)pw[idx - WG_E - 2*W1_E];
    }
}

__device__ __forceinline__ float sigm(float x)  { return 1.0f/(1.0f+__expf(-x)); }
__device__ __forceinline__ float tanh_(float x) { return 1.0f - 2.0f/(1.0f+__expf(2.0f*x)); }

// stage one 32KB panel cooperatively (8 waves x 4 gll16). LDS dest linear;
// global source carries the inverse chunk-XOR permutation.
__device__ __forceinline__ void stage(const uint8_t* __restrict__ Wp,
                                      uint8_t* slot_, int w, int lane)
{
    #pragma unroll
    for (int i = 0; i < 4; ++i) {
        int d  = w*4096 + i*1024;              // wave-uniform LDS offset
        int dl = d + lane*16;
        int chunk = (dl>>7)&31;
        int sl    = (dl>>4)&7;
        int row   = ((dl>>12)<<3) | (sl ^ (chunk&7));
        int s     = row*512 + chunk*16;
        __builtin_amdgcn_global_load_lds(
            (const __attribute__((address_space(1))) uint32_t*)(Wp + s),
            (__attribute__((address_space(3))) uint32_t*)(slot_ + d),
            16, 0, 0);
    }
}

struct Bases { const uint8_t* p[4]; };

__device__ __forceinline__ Bases mkbases(const uint8_t* base, int off, int u2) {
    Bases b;
    #pragma unroll
    for (int j = 0; j < 4; ++j) b.p[j] = base + off + (u2 ^ (j<<5));
    return b;
}
__device__ __forceinline__ void ldA(f16x8* A, const Bases& aB) {
    #pragma unroll
    for (int ks = 0; ks < 16; ++ks)
        A[ks] = *(const f16x8*)(aB.p[ks&3] + ks*256);
}
__device__ __forceinline__ f32x16 gemm4(const Bases& bb, const f16x8* A, f32x16 acc) {
    #pragma unroll
    for (int ks = 0; ks < 16; ++ks) {
        f16x8 b = *(const f16x8*)(bb.p[ks&3] + ks*256);
        acc = __builtin_amdgcn_mfma_f32_32x32x16_f16(A[ks], b, acc, 0, 0, 0);
    }
    return acc;
}

// phase: wait compute-slot loads -> barrier -> stage 2-ahead -> compute
#define PH(SP, ...) do {                                                    \
    asm volatile("s_waitcnt vmcnt(4)" ::: "memory");                        \
    asm volatile("s_waitcnt lgkmcnt(0)" ::: "memory");                      \
    __builtin_amdgcn_s_barrier();                                           \
    asm volatile("" ::: "memory");                                          \
    { int sS = sC + 2; if (sS >= 3) sS -= 3;                                \
      stage(W + (size_t)(SP)*32768, Wb + sS*32768, w, lane); }              \
    { const uint8_t* pan = Wb + sC*32768;                                   \
      Bases bb = mkbases(pan, Bc, u2); (void)bb; __VA_ARGS__; }             \
    sC = (sC == 2) ? 0 : sC + 1;                                            \
} while (0)

__global__ __launch_bounds__(512, 1)
void gru_dec(const float* __restrict__ h_in, const _Float16* __restrict__ Wf,
             const float* __restrict__ gate_b, const float* __restrict__ out_b,
             const float* __restrict__ proj_b, float* __restrict__ out)
{
    __shared__ __align__(16) uint8_t lds[163840];
    uint8_t* Wb = lds + 65536;                 // 3 x 32KB panel ring
    const uint8_t* W = (const uint8_t*)Wf;

    const int tid  = threadIdx.x;
    const int lane = tid & 63;
    const int w    = tid >> 6;                 // 0..7
    const int g    = w >> 2;                   // row group 0/1
    const int wl   = w & 3;
    const int mhat = wl >> 1, nhat = wl & 1;
    const int kg   = lane >> 5, bl = lane & 31;
    uint8_t* Ht = lds + g*32768;               // [64 rows][256 f16], chunk-XOR
    const int row0 = blockIdx.x*128 + g*64;

    // ---- initial h: 512 threads cover 128 rows x 256 cols, f32 -> f16 ----
    {
        int r  = tid >> 2;                     // 0..127
        int lr = r & 63;
        uint8_t* gb2 = lds + (r>>6)*32768 + (lr>>3)*4096;
        int sl7 = lr & 7;
        const float* src = h_in + (size_t)(blockIdx.x*128 + r)*256 + (tid&3)*64;
        #pragma unroll
        for (int i = 0; i < 16; ++i) {
            float4 v = *(const float4*)(src + i*4);
            f16x4 p = {(_Float16)v.x,(_Float16)v.y,(_Float16)v.z,(_Float16)v.w};
            int c = (tid&3)*64 + i*4;
            int chunk = c>>3;
            *(f16x4*)(gb2 + chunk*128 + ((sl7 ^ (chunk&7))<<4) + (c&7)*2) = p;
        }
    }

    float rb[4], zb[4], ob2[4];
    #pragma unroll
    for (int k = 0; k < 4; ++k) {
        int c = k*64 + nhat*32 + bl;
        rb[k] = gate_b[c]; zb[k] = gate_b[256 + c]; ob2[k] = out_b[c];
    }
    const float pb = proj_b[nhat*32 + bl];

    // per-lane addressing constants
    const int u2 = ((bl&7) ^ kg) << 4;
    const int Bc = (nhat*4 + (bl>>3))*4096 + kg*128;     // B page base in panel
    const int Ac = (mhat*4 + (bl>>3))*4096 + kg*128;     // A page base in Ht
    const int q  = nhat*4 + (bl>>3);
    const int m16 = ((kg<<2) ^ q) << 4;
    const int E0 = mhat*16384 + q*128 + (bl&7)*2;
    uint8_t* X[4];
    #pragma unroll
    for (int j = 0; j < 4; ++j) X[j] = Ht + E0 + ((j*16) ^ m16);
    const Bases aB = mkbases(Ht, Ac, u2);

    __syncthreads();

    f16x8 A[16];
    ldA(A, aB);                                // A = h

    stage(W + 8*32768, Wb,         w, lane);   // prologue: panels 8,9
    stage(W + 9*32768, Wb + 32768, w, lane);
    int sC = 0;

    for (int t = 0; t < TSTEPS; ++t) {
        f16x16v oaH[4], zz[4], hold[4];

        // ---- W1 (panels 8..11): oaH_k = f16(h @ W1_k^T), acc transient ----
#define W1PH(SPAN, K)                                                         \
        PH(SPAN, { f32x16 acc = {}; acc = gemm4(bb, A, acc);                  \
            _Pragma("unroll")                                                 \
            for (int e = 0; e < 16; ++e) oaH[K][e] = (_Float16)acc[e]; })
        W1PH(10, 0); W1PH(11, 1); W1PH(4, 2); W1PH(5, 3);
#undef W1PH

        // ---- z gates (panels 4..7): zz_k f16 in regs ----
#define ZPH(SPAN, K)                                                          \
        PH(SPAN, { f32x16 acc = {}; acc = gemm4(bb, A, acc);                  \
            _Pragma("unroll")                                                 \
            for (int e = 0; e < 16; ++e)                                      \
                zz[K][e] = (_Float16)sigm(acc[e] + zb[K]); })
        ZPH(6, 0); ZPH(7, 1); ZPH(0, 2); ZPH(1, 3);
#undef ZPH

        // ---- r gates (panels 0..3): capture h_old, write rh over Ht band k ----
#define RPH(SPAN, K)                                                          \
        PH(SPAN, { f32x16 acc = {}; acc = gemm4(bb, A, acc);                  \
            _Pragma("unroll")                                                 \
            for (int e = 0; e < 16; ++e) {                                    \
                uint8_t* p = X[e&3] + (K)*1024 + (e>>2)*4096;                 \
                float hc = (float)*(const _Float16*)p;                        \
                hold[K][e] = (_Float16)hc;                                    \
                *(_Float16*)p = (_Float16)(sigm(acc[e] + rb[K]) * hc);        \
            } })
        RPH(2, 0); RPH(3, 1); RPH(12, 2); RPH(13, 3);
#undef RPH

        // ---- W2 (panels 12..15): acc = f32(oaH_k) + rh @ W2_k^T; combine ----
        PH(14, {
            ldA(A, aB);                                     // A = rh (all bands)
            asm volatile("s_waitcnt lgkmcnt(0)" ::: "memory");
            __builtin_amdgcn_s_barrier();                   // all waves loaded rh
            asm volatile("" ::: "memory");
            f32x16 acc;
            _Pragma("unroll")
            for (int e = 0; e < 16; ++e) acc[e] = (float)oaH[0][e];
            acc = gemm4(bb, A, acc);
            _Pragma("unroll")
            for (int e = 0; e < 16; ++e) {
                float u = tanh_(acc[e] + ob2[0]);
                float z = (float)zz[0][e];
                uint8_t* p = X[e&3] + 0*1024 + (e>>2)*4096;
                *(_Float16*)p = (_Float16)(z*(float)hold[0][e] + (1.0f - z)*u);
            } });
#define W2PH(SPAN, K)                                                         \
        PH(SPAN, { f32x16 acc;                                                \
            _Pragma("unroll")                                                 \
            for (int e = 0; e < 16; ++e) acc[e] = (float)oaH[K][e];           \
            acc = gemm4(bb, A, acc);                                          \
            _Pragma("unroll")                                                 \
            for (int e = 0; e < 16; ++e) {                                    \
                float u = tanh_(acc[e] + ob2[K]);                             \
                float z = (float)zz[K][e];                                    \
                uint8_t* p = X[e&3] + (K)*1024 + (e>>2)*4096;                 \
                *(_Float16*)p = (_Float16)(z*(float)hold[K][e] + (1.0f - z)*u); \
            } })
        W2PH(15, 1); W2PH(16, 2); W2PH(8, 3);
#undef W2PH

        // ---- proj (panel 16): A <- h_new; out_t = h_new @ Wp^T + pb ----
        PH(9, {
            ldA(A, aB);                                     // A = h_new
            f32x16 acc = {}; acc = gemm4(bb, A, acc);
            _Pragma("unroll")
            for (int e = 0; e < 16; ++e) {
                int row = mhat*32 + (e&3) + 8*(e>>2) + 4*kg;
                __builtin_nontemporal_store(acc[e] + pb,
                    &out[((size_t)(row0 + row)*TSTEPS + t)*64 + nhat*32 + bl]);
            } });
    }
}

extern "C" void kernel_launch(void* const* d_in, const int* in_sizes, int n_in,
                              void* d_out, int out_size, void* d_ws, size_t ws_size,
                              hipStream_t stream) {
    // inputs: 0:x(=12) 1:h 2:gate_w 3:gate_b 4:out_w 5:out_b 6:proj_w 7:proj_b
    const float* h  = (const float*)d_in[1];
    const float* gw = (const float*)d_in[2];
    const float* gb = (const float*)d_in[3];
    const float* ow = (const float*)d_in[4];
    const float* ob = (const float*)d_in[5];
    const float* pw = (const float*)d_in[6];
    const float* pb = (const float*)d_in[7];
    if (ws_size < (size_t)WS_F16_TOTAL * sizeof(_Float16)) return;
    _Float16* ws = (_Float16*)d_ws;

    hipLaunchKernelGGL(prep_weights, dim3((WS_F16_TOTAL + 255)/256), dim3(256), 0, stream,
                       gw, ow, pw, ws);
    hipLaunchKernelGGL(gru_dec, dim3(NROWS/128), dim3(512), 0, stream,
                       h, ws, gb, ob, pb, (float*)d_out);
}